// Round 1
// baseline (147.922 us; speedup 1.0000x reference)
//
#include <hip/hip_runtime.h>

namespace {

constexpr int   TT     = 2048;
constexpr int   BB     = 128;
constexpr int   CHUNK  = 64;                 // timesteps per chunk
constexpr int   NCHUNK = TT / CHUNK;         // 32
constexpr float DT     = 0.02f;
constexpr size_t HALF  = (size_t)TT * BB * 16;  // floats in the real half of d_out
constexpr int   NTERM  = 8;                  // Taylor degree for expm

// C = A @ B, complex 4x4, row-major flat [16]
__device__ __forceinline__ void cmm(const float* __restrict__ ar, const float* __restrict__ ai,
                                    const float* __restrict__ br, const float* __restrict__ bi,
                                    float* __restrict__ cr, float* __restrict__ ci) {
#pragma unroll
    for (int i = 0; i < 4; ++i) {
#pragma unroll
        for (int j = 0; j < 4; ++j) {
            float sr = 0.f, si = 0.f;
#pragma unroll
            for (int k = 0; k < 4; ++k) {
                const float xr = ar[i * 4 + k], xi = ai[i * 4 + k];
                const float yr = br[k * 4 + j], yi = bi[k * 4 + j];
                sr = fmaf(xr, yr, sr);
                sr = fmaf(-xi, yi, sr);
                si = fmaf(xr, yi, si);
                si = fmaf(xi, yr, si);
            }
            cr[i * 4 + j] = sr;
            ci[i * 4 + j] = si;
        }
    }
}

} // namespace

// ---------------------------------------------------------------------------
// K1: U[b,t] = expm(-i*DT*H[b,t]) for all (b,t); one thread per 4x4 matrix.
// A = -i*DT*(hr + i*hi) => A_real = DT*hi, A_imag = -DT*hr.
// Stores U into d_out: real at ((t*B+b)*16), imag at HALF + same.
// ---------------------------------------------------------------------------
__global__ __launch_bounds__(256) void k1_expm(const float* __restrict__ hr,
                                               const float* __restrict__ hi,
                                               float* __restrict__ out) {
    const int gid = blockIdx.x * 256 + threadIdx.x;   // gid = b*TT + t
    const int b = gid / TT;
    const int t = gid - b * TT;

    float a_r[16], a_i[16];
    {
        const float4* p4r = reinterpret_cast<const float4*>(hr) + (size_t)gid * 4;
        const float4* p4i = reinterpret_cast<const float4*>(hi) + (size_t)gid * 4;
#pragma unroll
        for (int v = 0; v < 4; ++v) {
            const float4 r  = p4r[v];
            const float4 im = p4i[v];
            a_r[v * 4 + 0] = DT * im.x;  a_i[v * 4 + 0] = -DT * r.x;
            a_r[v * 4 + 1] = DT * im.y;  a_i[v * 4 + 1] = -DT * r.y;
            a_r[v * 4 + 2] = DT * im.z;  a_i[v * 4 + 2] = -DT * r.z;
            a_r[v * 4 + 3] = DT * im.w;  a_i[v * 4 + 3] = -DT * r.w;
        }
    }

    // Horner: E = I; for k=N..1: E = (A@E)/k + I  -> degree-N Taylor of exp(A)
    float e_r[16], e_i[16];
#pragma unroll
    for (int e = 0; e < 16; ++e) {
        e_r[e] = (e % 5 == 0) ? 1.0f : 0.0f;
        e_i[e] = 0.0f;
    }
#pragma unroll
    for (int k = NTERM; k >= 1; --k) {
        float t_r[16], t_i[16];
        cmm(a_r, a_i, e_r, e_i, t_r, t_i);
        const float rk = 1.0f / (float)k;
#pragma unroll
        for (int e = 0; e < 16; ++e) {
            const float d = (e % 5 == 0) ? 1.0f : 0.0f;
            e_r[e] = fmaf(t_r[e], rk, d);
            e_i[e] = t_i[e] * rk;
        }
    }

    const size_t o = ((size_t)t * BB + b) * 16;
    float4* orp = reinterpret_cast<float4*>(out + o);
    float4* oip = reinterpret_cast<float4*>(out + HALF + o);
#pragma unroll
    for (int v = 0; v < 4; ++v) {
        orp[v] = make_float4(e_r[v * 4 + 0], e_r[v * 4 + 1], e_r[v * 4 + 2], e_r[v * 4 + 3]);
        oip[v] = make_float4(e_i[v * 4 + 0], e_i[v * 4 + 1], e_i[v * 4 + 2], e_i[v * 4 + 3]);
    }
}

// ---------------------------------------------------------------------------
// K2: in-place chunk-local inclusive prefix products.
// 16 lanes per chunk; lane q holds element (i=q>>2, j=q&3).
// After: d_out slot t = c*CHUNK+jj holds L = U[t] @ ... @ U[c*CHUNK].
// ---------------------------------------------------------------------------
__global__ __launch_bounds__(256) void k2_chunk(float* __restrict__ buf) {
    const int gid = blockIdx.x * 256 + threadIdx.x;
    const int cid = gid >> 4;              // chunk id: 0 .. BB*NCHUNK-1
    const int q   = gid & 15;
    const int b   = cid >> 5;              // cid / NCHUNK (NCHUNK==32)
    const int c   = cid & (NCHUNK - 1);
    const int i   = q >> 2, j = q & 3;

    const size_t mo = ((size_t)(c * CHUNK) * BB + b) * 16;   // chunk's first matrix
    float pr = buf[mo + q];
    float pi = buf[HALF + mo + q];

#pragma unroll 4
    for (int jj = 1; jj < CHUNK; ++jj) {
        const size_t o = mo + (size_t)jj * (BB * 16) + q;
        const float ur = buf[o];
        const float ui = buf[HALF + o];
        float nr = 0.f, ni = 0.f;
#pragma unroll
        for (int k = 0; k < 4; ++k) {
            const float ar = __shfl(ur, (i << 2) | k, 16);   // U[i][k]
            const float ai = __shfl(ui, (i << 2) | k, 16);
            const float br = __shfl(pr, (k << 2) | j, 16);   // P[k][j]
            const float bi = __shfl(pi, (k << 2) | j, 16);
            nr = fmaf(ar, br, nr);
            nr = fmaf(-ai, bi, nr);
            ni = fmaf(ar, bi, ni);
            ni = fmaf(ai, br, ni);
        }
        pr = nr;
        pi = ni;
        buf[o] = pr;
        buf[HALF + o] = pi;
    }
}

// ---------------------------------------------------------------------------
// K3: carries across chunks per batch. carry[b][0] = state0;
// carry[b][c] = L[b][c-1][CHUNK-1] @ carry[b][c-1].  16 lanes per batch.
// carries stored to d_ws as float2 (re, im): [b][c][q].
// ---------------------------------------------------------------------------
__global__ __launch_bounds__(256) void k3_carry(const float* __restrict__ buf,
                                                const float* __restrict__ sr,
                                                const float* __restrict__ si,
                                                float2* __restrict__ carry) {
    const int gid = blockIdx.x * 256 + threadIdx.x;  // 0 .. BB*16-1
    const int b = gid >> 4;
    const int q = gid & 15;
    const int i = q >> 2, j = q & 3;

    float cr = sr[b * 16 + q];
    float ci = si[b * 16 + q];
    carry[(size_t)b * NCHUNK * 16 + q] = make_float2(cr, ci);

#pragma unroll 4
    for (int c = 1; c < NCHUNK; ++c) {
        const size_t t = (size_t)c * CHUNK - 1;                 // last slot of chunk c-1
        const size_t o = (t * BB + b) * 16 + q;
        const float tr = buf[o];
        const float ti = buf[HALF + o];
        float nr = 0.f, ni = 0.f;
#pragma unroll
        for (int k = 0; k < 4; ++k) {
            const float ar = __shfl(tr, (i << 2) | k, 16);      // total[i][k]
            const float ai = __shfl(ti, (i << 2) | k, 16);
            const float br = __shfl(cr, (k << 2) | j, 16);      // carry[k][j]
            const float bi = __shfl(ci, (k << 2) | j, 16);
            nr = fmaf(ar, br, nr);
            nr = fmaf(-ai, bi, nr);
            ni = fmaf(ar, bi, ni);
            ni = fmaf(ai, br, ni);
        }
        cr = nr;
        ci = ni;
        carry[(size_t)b * NCHUNK * 16 + (size_t)c * 16 + q] = make_float2(cr, ci);
    }
}

// ---------------------------------------------------------------------------
// K4: finalize in place: out[t,b] = L[t,b] @ carry[b][t/CHUNK].
// One thread per matrix; gid = t*BB + b so d_out access is gid*16.
// ---------------------------------------------------------------------------
__global__ __launch_bounds__(256) void k4_final(float* __restrict__ buf,
                                                const float2* __restrict__ carry) {
    const int gid = blockIdx.x * 256 + threadIdx.x;   // t*BB + b
    const int b = gid & (BB - 1);
    const int t = gid >> 7;                            // BB == 128
    const int c = t / CHUNK;

    const size_t o = (size_t)gid * 16;
    float l_r[16], l_i[16];
    {
        const float4* p4r = reinterpret_cast<const float4*>(buf + o);
        const float4* p4i = reinterpret_cast<const float4*>(buf + HALF + o);
#pragma unroll
        for (int v = 0; v < 4; ++v) {
            const float4 r  = p4r[v];
            const float4 im = p4i[v];
            l_r[v * 4 + 0] = r.x;  l_i[v * 4 + 0] = im.x;
            l_r[v * 4 + 1] = r.y;  l_i[v * 4 + 1] = im.y;
            l_r[v * 4 + 2] = r.z;  l_i[v * 4 + 2] = im.z;
            l_r[v * 4 + 3] = r.w;  l_i[v * 4 + 3] = im.w;
        }
    }

    float c_r[16], c_i[16];
    {
        const float2* cp = carry + ((size_t)b * NCHUNK + c) * 16;
#pragma unroll
        for (int e = 0; e < 16; ++e) {
            const float2 v = cp[e];
            c_r[e] = v.x;
            c_i[e] = v.y;
        }
    }

    float o_r[16], o_i[16];
    cmm(l_r, l_i, c_r, c_i, o_r, o_i);

    float4* orp = reinterpret_cast<float4*>(buf + o);
    float4* oip = reinterpret_cast<float4*>(buf + HALF + o);
#pragma unroll
    for (int v = 0; v < 4; ++v) {
        orp[v] = make_float4(o_r[v * 4 + 0], o_r[v * 4 + 1], o_r[v * 4 + 2], o_r[v * 4 + 3]);
        oip[v] = make_float4(o_i[v * 4 + 0], o_i[v * 4 + 1], o_i[v * 4 + 2], o_i[v * 4 + 3]);
    }
}

extern "C" void kernel_launch(void* const* d_in, const int* in_sizes, int n_in,
                              void* d_out, int out_size, void* d_ws, size_t ws_size,
                              hipStream_t stream) {
    const float* hr = (const float*)d_in[0];
    const float* hi = (const float*)d_in[1];
    const float* sr = (const float*)d_in[2];
    const float* si = (const float*)d_in[3];
    float*  out   = (float*)d_out;
    float2* carry = (float2*)d_ws;   // needs BB*NCHUNK*16*8 = 512 KiB

    k1_expm <<<(BB * TT) / 256, 256, 0, stream>>>(hr, hi, out);
    k2_chunk<<<(BB * NCHUNK * 16) / 256, 256, 0, stream>>>(out);
    k3_carry<<<(BB * 16) / 256, 256, 0, stream>>>(out, sr, si, carry);
    k4_final<<<(BB * TT) / 256, 256, 0, stream>>>(out, carry);
}

// Round 2
// 134.212 us; speedup vs baseline: 1.1022x; 1.1022x over previous
//
#include <hip/hip_runtime.h>

namespace {

constexpr int    TT     = 2048;
constexpr int    BB     = 128;
constexpr int    CHUNK  = 16;                  // timesteps per chunk (== shfl scan width)
constexpr int    NCHUNK = TT / CHUNK;          // 128
constexpr float  DT     = 0.02f;
constexpr size_t HALF   = (size_t)TT * BB * 16;   // floats in real half of d_out

// C = A @ B, complex 4x4, row-major flat [16]
__device__ __forceinline__ void cmm(const float* __restrict__ ar, const float* __restrict__ ai,
                                    const float* __restrict__ br, const float* __restrict__ bi,
                                    float* __restrict__ cr, float* __restrict__ ci) {
#pragma unroll
    for (int i = 0; i < 4; ++i) {
#pragma unroll
        for (int j = 0; j < 4; ++j) {
            float sr = 0.f, si = 0.f;
#pragma unroll
            for (int k = 0; k < 4; ++k) {
                const float xr = ar[i * 4 + k], xi = ai[i * 4 + k];
                const float yr = br[k * 4 + j], yi = bi[k * 4 + j];
                sr = fmaf(xr, yr, sr);
                sr = fmaf(-xi, yi, sr);
                si = fmaf(xr, yi, si);
                si = fmaf(xi, yr, si);
            }
            cr[i * 4 + j] = sr;
            ci[i * 4 + j] = si;
        }
    }
}

} // namespace

// ---------------------------------------------------------------------------
// kA: fused expm + chunk-local inclusive prefix (Kogge-Stone over 16 lanes).
//   thread <-> matrix (b, t), t = c*CHUNK + sub, sub = lane&15.
//   expm via Paterson-Stockmeyer degree-6 Taylor (3 matmuls).
//   L written to d_out ([t*BB+b] layout, real half / imag half).
//   Chunk totals (sub==15) written to totals[cid][32].
// ---------------------------------------------------------------------------
__global__ __launch_bounds__(256) void kA_expm_scan(const float* __restrict__ hr,
                                                    const float* __restrict__ hi,
                                                    float* __restrict__ out,
                                                    float* __restrict__ totals) {
    const int gid  = blockIdx.x * 256 + threadIdx.x;
    const int sub  = gid & (CHUNK - 1);
    const int cid  = gid >> 4;              // b*NCHUNK + c
    const int b    = cid >> 7;              // / NCHUNK (==128)
    const int c    = cid & (NCHUNK - 1);
    const int t    = c * CHUNK + sub;
    const int lane = threadIdx.x & 63;

    // ---- load A = -i*DT*H: a_r = DT*hi, a_i = -DT*hr
    float a_r[16], a_i[16];
    {
        const size_t ho = ((size_t)b * TT + t) * 16;
        const float4* p4r = reinterpret_cast<const float4*>(hr + ho);
        const float4* p4i = reinterpret_cast<const float4*>(hi + ho);
#pragma unroll
        for (int v = 0; v < 4; ++v) {
            const float4 r  = p4r[v];
            const float4 im = p4i[v];
            a_r[v * 4 + 0] = DT * im.x;  a_i[v * 4 + 0] = -DT * r.x;
            a_r[v * 4 + 1] = DT * im.y;  a_i[v * 4 + 1] = -DT * r.y;
            a_r[v * 4 + 2] = DT * im.z;  a_i[v * 4 + 2] = -DT * r.z;
            a_r[v * 4 + 3] = DT * im.w;  a_i[v * 4 + 3] = -DT * r.w;
        }
    }

    // ---- expm: E = (I + A + A2/2) + A3 @ (I/6 + A/24 + A2/120 + A3/720)
    float a2r[16], a2i[16], a3r[16], a3i[16];
    cmm(a_r, a_i, a_r, a_i, a2r, a2i);
    cmm(a2r, a2i, a_r, a_i, a3r, a3i);

    float tr[16], ti[16];
#pragma unroll
    for (int e = 0; e < 16; ++e) {
        const float d = (e % 5 == 0) ? 1.0f : 0.0f;
        tr[e] = fmaf(a_r[e], 1.f / 24.f, d * (1.f / 6.f));
        tr[e] = fmaf(a2r[e], 1.f / 120.f, tr[e]);
        tr[e] = fmaf(a3r[e], 1.f / 720.f, tr[e]);
        ti[e] = a_i[e] * (1.f / 24.f);
        ti[e] = fmaf(a2i[e], 1.f / 120.f, ti[e]);
        ti[e] = fmaf(a3i[e], 1.f / 720.f, ti[e]);
    }

    float er[16], ei[16];
    cmm(a3r, a3i, tr, ti, er, ei);
#pragma unroll
    for (int e = 0; e < 16; ++e) {
        const float d = (e % 5 == 0) ? 1.0f : 0.0f;
        er[e] = er[e] + d + a_r[e] + 0.5f * a2r[e];
        ei[e] = ei[e] + a_i[e] + 0.5f * a2i[e];
    }

    // ---- Kogge-Stone inclusive prefix over the 16 lanes of the chunk.
    // P[sub] = U[sub] @ U[sub-1] @ ... @ U[0]; round d: P = P @ P[src=sub-d].
#pragma unroll
    for (int d = 1; d < CHUNK; d <<= 1) {
        int src = lane - d;
        if (src < 0) src = 0;               // clamped junk, discarded by select
        float qr[16], qi[16];
#pragma unroll
        for (int e = 0; e < 16; ++e) {
            qr[e] = __shfl(er[e], src, 64);
            qi[e] = __shfl(ei[e], src, 64);
        }
        float nr[16], ni[16];
        cmm(er, ei, qr, qi, nr, ni);
        const bool pred = (sub >= d);
#pragma unroll
        for (int e = 0; e < 16; ++e) {
            er[e] = pred ? nr[e] : er[e];
            ei[e] = pred ? ni[e] : ei[e];
        }
    }

    // ---- write L to d_out in final [t][b] layout
    {
        const size_t o = ((size_t)t * BB + b) * 16;
        float4* orp = reinterpret_cast<float4*>(out + o);
        float4* oip = reinterpret_cast<float4*>(out + HALF + o);
#pragma unroll
        for (int v = 0; v < 4; ++v) {
            orp[v] = make_float4(er[v * 4 + 0], er[v * 4 + 1], er[v * 4 + 2], er[v * 4 + 3]);
            oip[v] = make_float4(ei[v * 4 + 0], ei[v * 4 + 1], ei[v * 4 + 2], ei[v * 4 + 3]);
        }
    }

    // ---- chunk total
    if (sub == CHUNK - 1) {
        float* tp = totals + (size_t)cid * 32;
#pragma unroll
        for (int e = 0; e < 16; ++e) {
            tp[e]      = er[e];
            tp[16 + e] = ei[e];
        }
    }
}

// ---------------------------------------------------------------------------
// kC: carries. Per batch, inclusive prefix over M[0..NCHUNK-1] where
//   M[0] = state0[b], M[c] = total[b][c-1]  =>  carry[b][c] = prefix at c.
// Kogge-Stone (7 rounds) in LDS, SoA layout (conflict-free). 2 batches/block.
// ---------------------------------------------------------------------------
__global__ __launch_bounds__(256) void kC_carry(const float* __restrict__ totals,
                                                const float* __restrict__ sr,
                                                const float* __restrict__ si,
                                                float* __restrict__ carry) {
    __shared__ float sRe[32][256];
    __shared__ float sIm[32][256];

    const int tid  = threadIdx.x;
    const int bloc = tid >> 7;              // 0..1
    const int ct   = tid & (NCHUNK - 1);    // 0..127
    const int b    = blockIdx.x * 2 + bloc;

    float pr[16], pi[16];
    if (ct == 0) {
#pragma unroll
        for (int e = 0; e < 16; ++e) {
            pr[e] = sr[b * 16 + e];
            pi[e] = si[b * 16 + e];
        }
    } else {
        const float* tp = totals + ((size_t)b * NCHUNK + (ct - 1)) * 32;
#pragma unroll
        for (int e = 0; e < 16; ++e) {
            pr[e] = tp[e];
            pi[e] = tp[16 + e];
        }
    }

#pragma unroll
    for (int e = 0; e < 16; ++e) {
        sRe[e][tid]      = pr[e];
        sIm[e][tid]      = pi[e];
        sRe[e + 16][tid] = 0.f;   // unused rows kept to simplify indexing
        sIm[e + 16][tid] = 0.f;
    }
    __syncthreads();

#pragma unroll
    for (int d = 1; d < NCHUNK; d <<= 1) {
        int srcI = tid - d;
        if (ct < d) srcI = bloc << 7;       // clamped, discarded
        float qr[16], qi[16];
#pragma unroll
        for (int e = 0; e < 16; ++e) {
            qr[e] = sRe[e][srcI];
            qi[e] = sIm[e][srcI];
        }
        float nr[16], ni[16];
        cmm(pr, pi, qr, qi, nr, ni);
        const bool pred = (ct >= d);
#pragma unroll
        for (int e = 0; e < 16; ++e) {
            pr[e] = pred ? nr[e] : pr[e];
            pi[e] = pred ? ni[e] : pi[e];
        }
        __syncthreads();
#pragma unroll
        for (int e = 0; e < 16; ++e) {
            sRe[e][tid] = pr[e];
            sIm[e][tid] = pi[e];
        }
        __syncthreads();
    }

    float* cp = carry + ((size_t)b * NCHUNK + ct) * 32;
#pragma unroll
    for (int e = 0; e < 16; ++e) {
        cp[e]      = pr[e];
        cp[16 + e] = pi[e];
    }
}

// ---------------------------------------------------------------------------
// kD: finalize in place: out[t,b] = L[t,b] @ carry[b][t/CHUNK].
// ---------------------------------------------------------------------------
__global__ __launch_bounds__(256) void kD_final(float* __restrict__ buf,
                                                const float* __restrict__ carry) {
    const int gid = blockIdx.x * 256 + threadIdx.x;   // t*BB + b
    const int b = gid & (BB - 1);
    const int t = gid >> 7;
    const int c = t >> 4;                              // CHUNK == 16

    const size_t o = (size_t)gid * 16;
    float l_r[16], l_i[16];
    {
        const float4* p4r = reinterpret_cast<const float4*>(buf + o);
        const float4* p4i = reinterpret_cast<const float4*>(buf + HALF + o);
#pragma unroll
        for (int v = 0; v < 4; ++v) {
            const float4 r  = p4r[v];
            const float4 im = p4i[v];
            l_r[v * 4 + 0] = r.x;  l_i[v * 4 + 0] = im.x;
            l_r[v * 4 + 1] = r.y;  l_i[v * 4 + 1] = im.y;
            l_r[v * 4 + 2] = r.z;  l_i[v * 4 + 2] = im.z;
            l_r[v * 4 + 3] = r.w;  l_i[v * 4 + 3] = im.w;
        }
    }

    float c_r[16], c_i[16];
    {
        const float* cp = carry + ((size_t)b * NCHUNK + c) * 32;
#pragma unroll
        for (int e = 0; e < 16; ++e) {
            c_r[e] = cp[e];
            c_i[e] = cp[16 + e];
        }
    }

    float o_r[16], o_i[16];
    cmm(l_r, l_i, c_r, c_i, o_r, o_i);

    float4* orp = reinterpret_cast<float4*>(buf + o);
    float4* oip = reinterpret_cast<float4*>(buf + HALF + o);
#pragma unroll
    for (int v = 0; v < 4; ++v) {
        orp[v] = make_float4(o_r[v * 4 + 0], o_r[v * 4 + 1], o_r[v * 4 + 2], o_r[v * 4 + 3]);
        oip[v] = make_float4(o_i[v * 4 + 0], o_i[v * 4 + 1], o_i[v * 4 + 2], o_i[v * 4 + 3]);
    }
}

extern "C" void kernel_launch(void* const* d_in, const int* in_sizes, int n_in,
                              void* d_out, int out_size, void* d_ws, size_t ws_size,
                              hipStream_t stream) {
    const float* hr = (const float*)d_in[0];
    const float* hi = (const float*)d_in[1];
    const float* sr = (const float*)d_in[2];
    const float* si = (const float*)d_in[3];
    float* out    = (float*)d_out;
    float* totals = (float*)d_ws;                               // 16384*32*4 = 2 MiB
    float* carry  = (float*)d_ws + (size_t)BB * NCHUNK * 32;    // 2 MiB

    kA_expm_scan<<<(BB * TT) / 256, 256, 0, stream>>>(hr, hi, out, totals);
    kC_carry    <<<BB / 2, 256, 0, stream>>>(totals, sr, si, carry);
    kD_final    <<<(BB * TT) / 256, 256, 0, stream>>>(out, carry);
}

// Round 3
// 132.903 us; speedup vs baseline: 1.1130x; 1.0098x over previous
//
#include <hip/hip_runtime.h>

namespace {

constexpr int    TT     = 2048;
constexpr int    BB     = 128;
constexpr int    CHUNK  = 16;                  // timesteps per chunk (== shfl scan width)
constexpr int    NCHUNK = TT / CHUNK;          // 128
constexpr float  DT     = 0.02f;
constexpr size_t HALF   = (size_t)TT * BB * 16;   // floats per (real|imag) half

// C = A @ B, complex 4x4, row-major flat [16]
__device__ __forceinline__ void cmm(const float* __restrict__ ar, const float* __restrict__ ai,
                                    const float* __restrict__ br, const float* __restrict__ bi,
                                    float* __restrict__ cr, float* __restrict__ ci) {
#pragma unroll
    for (int i = 0; i < 4; ++i) {
#pragma unroll
        for (int j = 0; j < 4; ++j) {
            float sr = 0.f, si = 0.f;
#pragma unroll
            for (int k = 0; k < 4; ++k) {
                const float xr = ar[i * 4 + k], xi = ai[i * 4 + k];
                const float yr = br[k * 4 + j], yi = bi[k * 4 + j];
                sr = fmaf(xr, yr, sr);
                sr = fmaf(-xi, yi, sr);
                si = fmaf(xr, yi, si);
                si = fmaf(xi, yr, si);
            }
            cr[i * 4 + j] = sr;
            ci[i * 4 + j] = si;
        }
    }
}

} // namespace

// ---------------------------------------------------------------------------
// kA: fused expm + chunk-local inclusive prefix (Kogge-Stone over 16 lanes).
//   gid = b*TT + t exactly, so BOTH the H read and the L write are linear
//   (fully coalesced). L goes to d_ws in [b][t] layout (real half/imag half).
// ---------------------------------------------------------------------------
__global__ __launch_bounds__(256) void kA_expm_scan(const float* __restrict__ hr,
                                                    const float* __restrict__ hi,
                                                    float* __restrict__ L) {
    const int gid  = blockIdx.x * 256 + threadIdx.x;  // b*TT + t
    const int t    = gid & (TT - 1);
    const int sub  = t & (CHUNK - 1);
    const int lane = threadIdx.x & 63;

    // ---- load A = -i*DT*H: a_r = DT*hi, a_i = -DT*hr (coalesced)
    float a_r[16], a_i[16];
    {
        const float4* p4r = reinterpret_cast<const float4*>(hr) + (size_t)gid * 4;
        const float4* p4i = reinterpret_cast<const float4*>(hi) + (size_t)gid * 4;
#pragma unroll
        for (int v = 0; v < 4; ++v) {
            const float4 r  = p4r[v];
            const float4 im = p4i[v];
            a_r[v * 4 + 0] = DT * im.x;  a_i[v * 4 + 0] = -DT * r.x;
            a_r[v * 4 + 1] = DT * im.y;  a_i[v * 4 + 1] = -DT * r.y;
            a_r[v * 4 + 2] = DT * im.z;  a_i[v * 4 + 2] = -DT * r.z;
            a_r[v * 4 + 3] = DT * im.w;  a_i[v * 4 + 3] = -DT * r.w;
        }
    }

    // ---- expm: E = (I + A + A2/2) + A3 @ (I/6 + A/24 + A2/120 + A3/720)
    float a2r[16], a2i[16], a3r[16], a3i[16];
    cmm(a_r, a_i, a_r, a_i, a2r, a2i);
    cmm(a2r, a2i, a_r, a_i, a3r, a3i);

    float er[16], ei[16];
    {
        float tr[16], ti[16];
#pragma unroll
        for (int e = 0; e < 16; ++e) {
            const float d = (e % 5 == 0) ? 1.0f : 0.0f;
            tr[e] = fmaf(a_r[e], 1.f / 24.f, d * (1.f / 6.f));
            tr[e] = fmaf(a2r[e], 1.f / 120.f, tr[e]);
            tr[e] = fmaf(a3r[e], 1.f / 720.f, tr[e]);
            ti[e] = a_i[e] * (1.f / 24.f);
            ti[e] = fmaf(a2i[e], 1.f / 120.f, ti[e]);
            ti[e] = fmaf(a3i[e], 1.f / 720.f, ti[e]);
        }
        cmm(a3r, a3i, tr, ti, er, ei);
#pragma unroll
        for (int e = 0; e < 16; ++e) {
            const float d = (e % 5 == 0) ? 1.0f : 0.0f;
            er[e] = er[e] + d + a_r[e] + 0.5f * a2r[e];
            ei[e] = ei[e] + a_i[e] + 0.5f * a2i[e];
        }
    }

    // ---- Kogge-Stone inclusive prefix over the 16-lane chunk group.
#pragma unroll
    for (int d = 1; d < CHUNK; d <<= 1) {
        int src = lane - d;
        if (src < 0) src = 0;               // clamped junk, discarded by select
        float qr[16], qi[16];
#pragma unroll
        for (int e = 0; e < 16; ++e) {
            qr[e] = __shfl(er[e], src, 64);
            qi[e] = __shfl(ei[e], src, 64);
        }
        float nr[16], ni[16];
        cmm(er, ei, qr, qi, nr, ni);
        const bool pred = (sub >= d);
#pragma unroll
        for (int e = 0; e < 16; ++e) {
            er[e] = pred ? nr[e] : er[e];
            ei[e] = pred ? ni[e] : ei[e];
        }
    }

    // ---- write L linearly to ws ([b][t] layout) — coalesced
    {
        float4* orp = reinterpret_cast<float4*>(L) + (size_t)gid * 4;
        float4* oip = reinterpret_cast<float4*>(L + HALF) + (size_t)gid * 4;
#pragma unroll
        for (int v = 0; v < 4; ++v) {
            orp[v] = make_float4(er[v * 4 + 0], er[v * 4 + 1], er[v * 4 + 2], er[v * 4 + 3]);
            oip[v] = make_float4(ei[v * 4 + 0], ei[v * 4 + 1], ei[v * 4 + 2], ei[v * 4 + 3]);
        }
    }
}

// ---------------------------------------------------------------------------
// kC: carries. Per batch, inclusive prefix over M[0..NCHUNK-1]:
//   M[0] = state0[b], M[c] = chunk_total[b][c-1] = L[b][c*16 - 1].
// Kogge-Stone (7 rounds) in LDS (SoA, conflict-free). 2 batches/block.
// ---------------------------------------------------------------------------
__global__ __launch_bounds__(256) void kC_carry(const float* __restrict__ L,
                                                const float* __restrict__ sr,
                                                const float* __restrict__ si,
                                                float* __restrict__ carry) {
    __shared__ float sRe[16][256];
    __shared__ float sIm[16][256];

    const int tid  = threadIdx.x;
    const int bloc = tid >> 7;              // 0..1
    const int ct   = tid & (NCHUNK - 1);    // 0..127
    const int b    = blockIdx.x * 2 + bloc;

    float pr[16], pi[16];
    if (ct == 0) {
#pragma unroll
        for (int e = 0; e < 16; ++e) {
            pr[e] = sr[b * 16 + e];
            pi[e] = si[b * 16 + e];
        }
    } else {
        const size_t o = ((size_t)b * TT + (size_t)ct * CHUNK - 1) * 16;
#pragma unroll
        for (int e = 0; e < 16; ++e) {
            pr[e] = L[o + e];
            pi[e] = L[HALF + o + e];
        }
    }

#pragma unroll
    for (int e = 0; e < 16; ++e) {
        sRe[e][tid] = pr[e];
        sIm[e][tid] = pi[e];
    }
    __syncthreads();

#pragma unroll
    for (int d = 1; d < NCHUNK; d <<= 1) {
        int srcI = tid - d;
        if (ct < d) srcI = bloc << 7;       // clamped, discarded
        float qr[16], qi[16];
#pragma unroll
        for (int e = 0; e < 16; ++e) {
            qr[e] = sRe[e][srcI];
            qi[e] = sIm[e][srcI];
        }
        float nr[16], ni[16];
        cmm(pr, pi, qr, qi, nr, ni);
        const bool pred = (ct >= d);
#pragma unroll
        for (int e = 0; e < 16; ++e) {
            pr[e] = pred ? nr[e] : pr[e];
            pi[e] = pred ? ni[e] : pi[e];
        }
        __syncthreads();
#pragma unroll
        for (int e = 0; e < 16; ++e) {
            sRe[e][tid] = pr[e];
            sIm[e][tid] = pi[e];
        }
        __syncthreads();
    }

    float* cp = carry + ((size_t)b * NCHUNK + ct) * 32;
#pragma unroll
    for (int e = 0; e < 16; ++e) {
        cp[e]      = pr[e];
        cp[16 + e] = pi[e];
    }
}

// ---------------------------------------------------------------------------
// kD: out[t,b] = L[b,t] @ carry[b][t/16], transposing [b][t] -> [t][b] through
// LDS so both the global read and the global write are coalesced.
// Tile: 16 t x 16 b matrices per block (256 threads, 1 matrix/thread).
// LDS element-major with row pad 17 -> <=2-way bank aliasing (free).
// ---------------------------------------------------------------------------
__global__ __launch_bounds__(256) void kD_final(const float* __restrict__ L,
                                                const float* __restrict__ carry,
                                                float* __restrict__ out) {
    __shared__ float lds[32 * 16 * 17];     // [e 0..31][bloc 0..15][tloc 0..15(+pad)]

    const int bid   = blockIdx.x;           // 0..1023
    const int tileT = bid & (NCHUNK - 1);   // == chunk index c
    const int tileB = bid >> 7;             // 0..7
    const int t0 = tileT * 16, b0 = tileB * 16;
    const int tid = threadIdx.x;

    // ---- phase 1: read L coalesced, multiply by carry, stage to LDS
    {
        const int bloc = tid >> 4, tloc = tid & 15;
        const size_t li = ((size_t)(b0 + bloc) * TT + (t0 + tloc)) * 16;

        float l_r[16], l_i[16];
        const float4* p4r = reinterpret_cast<const float4*>(L + li);
        const float4* p4i = reinterpret_cast<const float4*>(L + HALF + li);
#pragma unroll
        for (int v = 0; v < 4; ++v) {
            const float4 r  = p4r[v];
            const float4 im = p4i[v];
            l_r[v * 4 + 0] = r.x;  l_i[v * 4 + 0] = im.x;
            l_r[v * 4 + 1] = r.y;  l_i[v * 4 + 1] = im.y;
            l_r[v * 4 + 2] = r.z;  l_i[v * 4 + 2] = im.z;
            l_r[v * 4 + 3] = r.w;  l_i[v * 4 + 3] = im.w;
        }

        float c_r[16], c_i[16];
        const float* cp = carry + ((size_t)(b0 + bloc) * NCHUNK + tileT) * 32;
#pragma unroll
        for (int e = 0; e < 16; ++e) {
            c_r[e] = cp[e];
            c_i[e] = cp[16 + e];
        }

        float o_r[16], o_i[16];
        cmm(l_r, l_i, c_r, c_i, o_r, o_i);

        const int slot = bloc * 17 + tloc;
#pragma unroll
        for (int e = 0; e < 16; ++e) {
            lds[e * 272 + slot]        = o_r[e];
            lds[(e + 16) * 272 + slot] = o_i[e];
        }
    }
    __syncthreads();

    // ---- phase 2: read transposed from LDS, write out coalesced in [t][b]
    {
        const int u = tid >> 4;             // t offset in tile
        const int v = tid & 15;             // b offset in tile
        const int slot = v * 17 + u;

        float r2[16], i2[16];
#pragma unroll
        for (int e = 0; e < 16; ++e) {
            r2[e] = lds[e * 272 + slot];
            i2[e] = lds[(e + 16) * 272 + slot];
        }

        const size_t oi = ((size_t)(t0 + u) * BB + (b0 + v)) * 16;
        float4* orp = reinterpret_cast<float4*>(out + oi);
        float4* oip = reinterpret_cast<float4*>(out + HALF + oi);
#pragma unroll
        for (int w = 0; w < 4; ++w) {
            orp[w] = make_float4(r2[w * 4 + 0], r2[w * 4 + 1], r2[w * 4 + 2], r2[w * 4 + 3]);
            oip[w] = make_float4(i2[w * 4 + 0], i2[w * 4 + 1], i2[w * 4 + 2], i2[w * 4 + 3]);
        }
    }
}

extern "C" void kernel_launch(void* const* d_in, const int* in_sizes, int n_in,
                              void* d_out, int out_size, void* d_ws, size_t ws_size,
                              hipStream_t stream) {
    const float* hr = (const float*)d_in[0];
    const float* hi = (const float*)d_in[1];
    const float* sr = (const float*)d_in[2];
    const float* si = (const float*)d_in[3];
    float* out   = (float*)d_out;
    float* L     = (float*)d_ws;                       // 33.5 MB ([b][t], re|im halves)
    float* carry = (float*)d_ws + 2 * HALF;            // 2 MB

    kA_expm_scan<<<(BB * TT) / 256, 256, 0, stream>>>(hr, hi, L);
    kC_carry    <<<BB / 2, 256, 0, stream>>>(L, sr, si, carry);
    kD_final    <<<(BB * TT) / 256, 256, 0, stream>>>(L, carry, out);
}